// Round 11
// baseline (410.049 us; speedup 1.0000x reference)
//
#include <hip/hip_runtime.h>

#define N_NODES 100000
#define N_EDGES 1600000
#define D 128
#define DE 32
#define SCAN_CHUNK 1024
#define N_CHUNKS ((N_NODES + SCAN_CHUNK - 1) / SCAN_CHUNK)  // 98

// NOTE on eps: reference divides by sqrt(deg_in*deg_out)+1e-10 with both
// degrees >= 1, so the +1e-10 is a 1e-10 relative perturbation — far below
// f32 rounding. We factor w = ew * rsqrt(di) * rsqrt(do); rdo is uniform per
// dst-node, so rows accumulate with w' = ew*rdi[src] and scale by rdo once.
//
// NOTE on bf16 gather (R9): neighbor-sum reads bf16(x) (RNE) with f32
// accumulation; measured absmax 0.0039 (unchanged vs f32) vs 0.019 threshold.
//
// R11: CSR records are wave-uniform -> readfirstlane + scalar-pipe loads
// (s_load_dwordx4) replace vector load + ds_bpermute broadcasts; 2 dims/lane
// (u32 = 2 bf16) halves vector-mem instructions.

__device__ inline float bflo(unsigned u) {
  return __uint_as_float(u << 16);
}
__device__ inline float bfhi(unsigned u) {
  return __uint_as_float(u & 0xFFFF0000u);
}
__device__ inline unsigned pk_bf2(float lo, float hi) {
  unsigned a = __float_as_uint(lo), b = __float_as_uint(hi);
  a = (a + 0x7FFFu + ((a >> 16) & 1)) >> 16;  // RNE
  b = (b + 0x7FFFu + ((b >> 16) & 1)) >> 16;
  return a | (b << 16);
}

// ---------------------------------------------------------------------------
// K1: zero deg replicas + cursor (contiguous 5N region).
__global__ __launch_bounds__(256) void init_kernel(int* __restrict__ z) {
  int idx = blockIdx.x * 256 + threadIdx.x;
  if (idx < 5 * N_NODES) z[idx] = 0;
}

// ---------------------------------------------------------------------------
// K2: per-edge cursor position atomic ONLY (1.6M atomics). 2 edges/thread.
__global__ __launch_bounds__(256) void pos_kernel(
    const int4* __restrict__ el2, int* __restrict__ cursor,
    int2* __restrict__ pos2) {
  int i = blockIdx.x * 256 + threadIdx.x;  // edge-pair index
  if (i >= N_EDGES / 2) return;
  int4 e = el2[i];
  int2 p;
  p.x = atomicAdd(&cursor[e.y], 1);
  p.y = atomicAdd(&cursor[e.w], 1);
  pos2[i] = p;
}

// ---------------------------------------------------------------------------
// K3a: per-1024-chunk exclusive scan of counts(=cursor) -> partial, totals.
__global__ __launch_bounds__(256) void scan1_kernel(
    const int* __restrict__ counts, int* __restrict__ partial,
    int* __restrict__ blocksum) {
  __shared__ int lds[256];
  int t = threadIdx.x;
  int base = blockIdx.x * SCAN_CHUNK + t * 4;
  int c[4];
  int s = 0;
#pragma unroll
  for (int k = 0; k < 4; k++) {
    c[k] = (base + k < N_NODES) ? counts[base + k] : 0;
    s += c[k];
  }
  lds[t] = s;
  __syncthreads();
  for (int off = 1; off < 256; off <<= 1) {
    int tmp = (t >= off) ? lds[t - off] : 0;
    __syncthreads();
    lds[t] += tmp;
    __syncthreads();
  }
  int run = lds[t] - s;
#pragma unroll
  for (int k = 0; k < 4; k++) {
    int v = base + k;
    if (v < N_NODES) partial[v] = run;
    run += c[k];
  }
  if (t == 255) blocksum[blockIdx.x] = lds[255];
}

// ---------------------------------------------------------------------------
// K3b: exclusive scan of the 98 chunk totals.
__global__ __launch_bounds__(128) void scan2_kernel(
    const int* __restrict__ blocksum, int* __restrict__ blockoff) {
  __shared__ int lds[128];
  int t = threadIdx.x;
  int v = (t < N_CHUNKS) ? blocksum[t] : 0;
  lds[t] = v;
  __syncthreads();
  for (int off = 1; off < 128; off <<= 1) {
    int tmp = (t >= off) ? lds[t - off] : 0;
    __syncthreads();
    lds[t] += tmp;
    __syncthreads();
  }
  if (t < N_CHUNKS) blockoff[t] = lds[t] - v;
}

// ---------------------------------------------------------------------------
// K4: place 16B AoS records {src, eid, ew, 0} at start[dst]+pos + deg_in
// replica atomics.
__global__ __launch_bounds__(256) void place_kernel(
    const int4* __restrict__ el2, const float2* __restrict__ ew2,
    const int2* __restrict__ pos2, const int* __restrict__ partial,
    const int* __restrict__ blockoff, float* __restrict__ deg4,
    int4* __restrict__ rec) {
  int i = blockIdx.x * 256 + threadIdx.x;  // edge-pair index
  if (i >= N_EDGES / 2) return;
  int4 e = el2[i];
  float2 w = ew2[i];
  int2 p = pos2[i];
  int r0 = (threadIdx.x & 3) * N_NODES;
  atomicAdd(&deg4[r0 + e.x], w.x);
  atomicAdd(&deg4[r0 + e.z], w.y);
  int4 rA, rB;
  rA.x = e.x; rA.y = 2 * i;     rA.z = __float_as_int(w.x); rA.w = 0;
  rB.x = e.z; rB.y = 2 * i + 1; rB.z = __float_as_int(w.y); rB.w = 0;
  rec[partial[e.y] + blockoff[e.y >> 10] + p.x] = rA;
  rec[partial[e.w] + blockoff[e.w >> 10] + p.y] = rB;
}

// ---------------------------------------------------------------------------
// K5: finalize rdi = rsqrt(1 + sum of 4 deg replicas).
__global__ __launch_bounds__(256) void rdi_kernel(
    const float* __restrict__ deg4, float* __restrict__ rdi) {
  int v = blockIdx.x * 256 + threadIdx.x;
  if (v >= N_NODES) return;
  rdi[v] = rsqrtf(1.f + deg4[v] + deg4[N_NODES + v] + deg4[2 * N_NODES + v] +
                  deg4[3 * N_NODES + v]);
}

// ---------------------------------------------------------------------------
// K6: xh = bf16(x) table (RNE), 8 elems/thread.
__global__ __launch_bounds__(256) void xh_kernel(
    const float4* __restrict__ x4, uint4* __restrict__ xh4) {
  int i = blockIdx.x * 256 + threadIdx.x;
  if (i >= N_NODES * D / 8) return;
  float4 f0 = x4[2 * i], f1 = x4[2 * i + 1];
  uint4 o;
  o.x = pk_bf2(f0.x, f0.y);
  o.y = pk_bf2(f0.z, f0.w);
  o.z = pk_bf2(f1.x, f1.y);
  o.w = pk_bf2(f1.z, f1.w);
  xh4[i] = o;
}

// ---------------------------------------------------------------------------
// K7: single-pass fused gather (ef + x + row epilogue). One wave per node.
// All CSR record fields are wave-uniform: start/cnt go through readfirstlane
// so rec[]/rdi[] compile to scalar-pipe loads (s_load_dwordx4) — no
// ds_bpermute broadcasts, no end-of-loop butterflies (dsum/wsv are uniform).
// Lane l owns dims 2l,2l+1: one u32 (2xbf16) vector load per x-row.
// ef reads nt-hinted (zero reuse); epilogue uses transposed W_edge in LDS
// (wet[32][132], float2 reads = 2-way conflict = free) and a per-wave gbuf
// for g-broadcast (wave-private, no barrier).
template <bool BF16>
__global__ __launch_bounds__(256) void gather_fused_kernel(
    const float* __restrict__ x, const ushort* __restrict__ xh,
    const float* __restrict__ ef, const int* __restrict__ partial,
    const int* __restrict__ blockoff, const int* __restrict__ counts,
    const int4* __restrict__ rec, const float* __restrict__ rdi,
    const float* __restrict__ W_edge, const float* __restrict__ b_edge,
    float* __restrict__ out) {
  __shared__ __align__(16) float wet[DE * 132];  // wet[k][d] = W_edge[d][k]
  __shared__ float beS[128];
  __shared__ float gbuf[4][DE];
  int t = threadIdx.x;
  for (int idx = t; idx < D * DE; idx += 256) {
    int d = idx >> 5, k = idx & 31;
    wet[k * 132 + d] = W_edge[idx];
  }
  if (t < 128) beS[t] = b_edge[t];
  __syncthreads();

  int wid = t >> 6, lane = t & 63;
  int v = blockIdx.x * 4 + wid;
  if (v >= N_NODES) return;  // never taken (25000*4 == N_NODES), safety only
  int start = __builtin_amdgcn_readfirstlane(partial[v] + blockoff[v >> 10]);
  int cnt = __builtin_amdgcn_readfirstlane(counts[v]);

  float A0 = 0.f, A1 = 0.f, B0 = 0.f, B1 = 0.f;
  float C0 = 0.f, C1 = 0.f, E0 = 0.f, E1 = 0.f;
  float ga = 0.f, gb = 0.f, dsum = 0.f, wsv = 0.f;
  int lane31 = lane & 31;
  bool lowhalf = lane < 32;

  int i = 0;
  for (; i + 4 <= cnt; i += 4) {
    int4 r0 = rec[start + i];      // uniform -> s_load_dwordx4
    int4 r1 = rec[start + i + 1];
    int4 r2 = rec[start + i + 2];
    int4 r3 = rec[start + i + 3];
    float wr0 = __int_as_float(r0.z), wr1 = __int_as_float(r1.z);
    float wr2 = __int_as_float(r2.z), wr3 = __int_as_float(r3.z);
    float w0 = wr0 * rdi[r0.x];    // rdi: uniform -> s_load_dword
    float w1 = wr1 * rdi[r1.x];
    float w2 = wr2 * rdi[r2.x];
    float w3 = wr3 * rdi[r3.x];
    dsum += (wr0 + wr1) + (wr2 + wr3);
    wsv += (w0 + w1) + (w2 + w3);
    // ef: two half-wave pairs
    float wA = lowhalf ? w0 : w1;
    int eA = lowhalf ? r0.y : r1.y;
    float wB = lowhalf ? w2 : w3;
    int eB = lowhalf ? r2.y : r3.y;
    ga = fmaf(wA, __builtin_nontemporal_load(&ef[(size_t)eA * DE + lane31]),
              ga);
    gb = fmaf(wB, __builtin_nontemporal_load(&ef[(size_t)eB * DE + lane31]),
              gb);
    // x rows: 1 u32 (2 bf16) or 1 float2 per row per lane
    if (BF16) {
      unsigned u0 = ((const unsigned*)(xh + (size_t)r0.x * D))[lane];
      unsigned u1 = ((const unsigned*)(xh + (size_t)r1.x * D))[lane];
      unsigned u2 = ((const unsigned*)(xh + (size_t)r2.x * D))[lane];
      unsigned u3 = ((const unsigned*)(xh + (size_t)r3.x * D))[lane];
      A0 = fmaf(w0, bflo(u0), A0); A1 = fmaf(w0, bfhi(u0), A1);
      B0 = fmaf(w1, bflo(u1), B0); B1 = fmaf(w1, bfhi(u1), B1);
      C0 = fmaf(w2, bflo(u2), C0); C1 = fmaf(w2, bfhi(u2), C1);
      E0 = fmaf(w3, bflo(u3), E0); E1 = fmaf(w3, bfhi(u3), E1);
    } else {
      float2 u0 = ((const float2*)(x + (size_t)r0.x * D))[lane];
      float2 u1 = ((const float2*)(x + (size_t)r1.x * D))[lane];
      float2 u2 = ((const float2*)(x + (size_t)r2.x * D))[lane];
      float2 u3 = ((const float2*)(x + (size_t)r3.x * D))[lane];
      A0 = fmaf(w0, u0.x, A0); A1 = fmaf(w0, u0.y, A1);
      B0 = fmaf(w1, u1.x, B0); B1 = fmaf(w1, u1.y, B1);
      C0 = fmaf(w2, u2.x, C0); C1 = fmaf(w2, u2.y, C1);
      E0 = fmaf(w3, u3.x, E0); E1 = fmaf(w3, u3.y, E1);
    }
  }
  for (; i < cnt; ++i) {
    int4 r0 = rec[start + i];
    float wr0 = __int_as_float(r0.z);
    float w0 = wr0 * rdi[r0.x];
    dsum += wr0;
    wsv += w0;
    if (lowhalf)
      ga = fmaf(w0, __builtin_nontemporal_load(&ef[(size_t)r0.y * DE + lane31]),
                ga);
    if (BF16) {
      unsigned u0 = ((const unsigned*)(xh + (size_t)r0.x * D))[lane];
      A0 = fmaf(w0, bflo(u0), A0);
      A1 = fmaf(w0, bfhi(u0), A1);
    } else {
      float2 u0 = ((const float2*)(x + (size_t)r0.x * D))[lane];
      A0 = fmaf(w0, u0.x, A0);
      A1 = fmaf(w0, u0.y, A1);
    }
  }
  float a0 = (A0 + B0) + (C0 + E0);
  float a1 = (A1 + B1) + (C1 + E1);

  float rdo = rsqrtf(1.f + dsum);  // dsum/wsv uniform: no reduction needed
  float gfull = ga + gb;
  gfull += __shfl(gfull, (lane + 32) & 63);  // lanes 0..31 hold full g_k
  if (lowhalf) gbuf[wid][lane] = gfull;      // wave-private, no barrier

  // epilogue (pre-rdo accumulation; one scale at the end)
  size_t ro = (size_t)v * D;
  float xs0, xs1;
  if (BF16) {
    unsigned u = ((const unsigned*)(xh + ro))[lane];
    xs0 = bflo(u);
    xs1 = bfhi(u);
  } else {
    float2 u = ((const float2*)(x + ro))[lane];
    xs0 = u.x;
    xs1 = u.y;
  }
  float rdiv = rdi[v];
  float2 be = *(const float2*)&beS[2 * lane];
  float s0 = a0 + rdiv * xs0 + wsv * be.x;
  float s1 = a1 + rdiv * xs1 + wsv * be.y;
#pragma unroll
  for (int k = 0; k < DE; ++k) {
    float gk = gbuf[wid][k];  // uniform LDS read -> broadcast
    float2 wv = *(const float2*)&wet[k * 132 + 2 * lane];
    s0 = fmaf(gk, wv.x, s0);
    s1 = fmaf(gk, wv.y, s1);
  }
  ((float2*)(out + ro))[lane] = make_float2(rdo * s0, rdo * s1);
}

// ---------------------------------------------------------------------------
// K8: in-place per-128-row-tile SGEMM: out = relu(out @ W_lin^T + b_lin).
// __launch_bounds__(256,3) + rolled kq-loop + one-b-at-a-time keeps VGPR low
// (R7 failure: 256 VGPR, 8.8% occupancy).
__global__ __launch_bounds__(256, 3) void gemm2_kernel(
    const float* __restrict__ W_lin, const float* __restrict__ b_lin,
    float* __restrict__ out) {
  __shared__ __align__(16) float xs[128 * 32];
  __shared__ __align__(16) float wl[128 * 32];
  int t = threadIdx.x;
  int tn = t & 15, tm = t >> 4;
  int m0 = 4 * tm, n0 = 4 * tn;
  int vbase = blockIdx.x * 128;
  float acc[8][8] = {};

  for (int ks = 0; ks < D; ks += 32) {
    __syncthreads();
#pragma unroll
    for (int i = 0; i < 4; ++i) {
      int f = t + i * 256;
      int r = f >> 3, kq = f & 7;
      int sw = (4 * kq) ^ (4 * ((r >> 2) & 7));
      float4 xv = make_float4(0.f, 0.f, 0.f, 0.f);
      if (vbase + r < N_NODES)
        xv = *(const float4*)&out[(size_t)(vbase + r) * D + ks + 4 * kq];
      *(float4*)&xs[r * 32 + sw] = xv;
      *(float4*)&wl[r * 32 + sw] = *(const float4*)&W_lin[r * D + ks + 4 * kq];
    }
    __syncthreads();
#pragma unroll 1
    for (int kq = 0; kq < 8; ++kq) {
      int sa = (4 * kq) ^ (4 * (tm & 7));
      int sb = (4 * kq) ^ (4 * (tn & 7));
      float4 a[8];
#pragma unroll
      for (int i = 0; i < 4; ++i) {
        a[i] = *(const float4*)&xs[(m0 + i) * 32 + sa];
        a[4 + i] = *(const float4*)&xs[(m0 + 64 + i) * 32 + sa];
      }
#pragma unroll
      for (int j = 0; j < 8; ++j) {
        int rj = (j < 4) ? (n0 + j) : (n0 + 60 + j);
        float4 b = *(const float4*)&wl[rj * 32 + sb];
#pragma unroll
        for (int i = 0; i < 8; ++i) {
          acc[i][j] += a[i].x * b.x + a[i].y * b.y + a[i].z * b.z +
                       a[i].w * b.w;
        }
      }
    }
  }

  float bl[8];
#pragma unroll
  for (int j = 0; j < 4; ++j) {
    bl[j] = b_lin[n0 + j];
    bl[4 + j] = b_lin[n0 + 64 + j];
  }
#pragma unroll
  for (int i = 0; i < 8; ++i) {
    int m = vbase + m0 + (i < 4 ? i : 64 + i - 4);
    if (m >= N_NODES) continue;
    float4 o0, o1;
    o0.x = fmaxf(acc[i][0] + bl[0], 0.f);
    o0.y = fmaxf(acc[i][1] + bl[1], 0.f);
    o0.z = fmaxf(acc[i][2] + bl[2], 0.f);
    o0.w = fmaxf(acc[i][3] + bl[3], 0.f);
    o1.x = fmaxf(acc[i][4] + bl[4], 0.f);
    o1.y = fmaxf(acc[i][5] + bl[5], 0.f);
    o1.z = fmaxf(acc[i][6] + bl[6], 0.f);
    o1.w = fmaxf(acc[i][7] + bl[7], 0.f);
    *(float4*)&out[(size_t)m * D + n0] = o0;
    *(float4*)&out[(size_t)m * D + n0 + 64] = o1;
  }
}

// ---------------------------------------------------------------------------
extern "C" void kernel_launch(void* const* d_in, const int* in_sizes, int n_in,
                              void* d_out, int out_size, void* d_ws,
                              size_t ws_size, hipStream_t stream) {
  const float* x      = (const float*)d_in[0];
  const int*   el     = (const int*)d_in[1];
  const float* ew     = (const float*)d_in[2];
  const float* ef     = (const float*)d_in[3];
  const float* W_lin  = (const float*)d_in[4];
  const float* b_lin  = (const float*)d_in[5];
  const float* W_edge = (const float*)d_in[6];
  const float* b_edge = (const float*)d_in[7];

  float* outp = (float*)d_out;  // fused gather writes rows; gemm2 in place

  // workspace layout (~60.4 MB with xh; fallback ~34.8 MB without)
  char* base = (char*)d_ws;
  size_t off = 0;
  int4* rec      = (int4*)(base + off); off += (size_t)N_EDGES * 16;
  ushort* xh     = (ushort*)(base + off); off += (size_t)N_NODES * D * 2;
  int*  pos      = (int*)(base + off);  off += (size_t)N_EDGES * 4;
  float* deg4    = (float*)(base + off); off += (size_t)4 * N_NODES * 4;
  int*  cursor   = (int*)(base + off);  off += (size_t)N_NODES * 4;
  int*  partial  = (int*)(base + off);  off += (size_t)N_NODES * 4;
  int*  blocksum = (int*)(base + off);  off += 512;
  int*  blockoff = (int*)(base + off);  off += 512;
  float* rdi     = (float*)(base + off); off += (size_t)N_NODES * 4;
  const size_t REQ_FAST = off;
  bool fast = (ws_size >= REQ_FAST);
  if (!fast) {
    // fallback layout: drop xh, shift everything after it down 25.6MB
    off = (size_t)N_EDGES * 16;
    pos      = (int*)(base + off);  off += (size_t)N_EDGES * 4;
    deg4     = (float*)(base + off); off += (size_t)4 * N_NODES * 4;
    cursor   = (int*)(base + off);  off += (size_t)N_NODES * 4;
    partial  = (int*)(base + off);  off += (size_t)N_NODES * 4;
    blocksum = (int*)(base + off);  off += 512;
    blockoff = (int*)(base + off);  off += 512;
    rdi      = (float*)(base + off); off += (size_t)N_NODES * 4;
    xh       = nullptr;
  }

  hipLaunchKernelGGL(init_kernel, dim3((5 * N_NODES + 255) / 256), dim3(256),
                     0, stream, (int*)deg4);
  hipLaunchKernelGGL(pos_kernel, dim3((N_EDGES / 2 + 255) / 256), dim3(256), 0,
                     stream, (const int4*)el, cursor, (int2*)pos);
  hipLaunchKernelGGL(scan1_kernel, dim3(N_CHUNKS), dim3(256), 0, stream,
                     cursor, partial, blocksum);
  hipLaunchKernelGGL(scan2_kernel, dim3(1), dim3(128), 0, stream, blocksum,
                     blockoff);
  hipLaunchKernelGGL(place_kernel, dim3((N_EDGES / 2 + 255) / 256), dim3(256),
                     0, stream, (const int4*)el, (const float2*)ew,
                     (const int2*)pos, partial, blockoff, deg4, rec);
  hipLaunchKernelGGL(rdi_kernel, dim3((N_NODES + 255) / 256), dim3(256), 0,
                     stream, deg4, rdi);
  if (fast) {
    hipLaunchKernelGGL(xh_kernel, dim3((N_NODES * D / 8 + 255) / 256),
                       dim3(256), 0, stream, (const float4*)x, (uint4*)xh);
    hipLaunchKernelGGL(gather_fused_kernel<true>, dim3((N_NODES + 3) / 4),
                       dim3(256), 0, stream, x, xh, ef, partial, blockoff,
                       cursor, rec, rdi, W_edge, b_edge, outp);
  } else {
    hipLaunchKernelGGL(gather_fused_kernel<false>, dim3((N_NODES + 3) / 4),
                       dim3(256), 0, stream, x, xh, ef, partial, blockoff,
                       cursor, rec, rdi, W_edge, b_edge, outp);
  }
  hipLaunchKernelGGL(gemm2_kernel, dim3((N_NODES + 127) / 128), dim3(256), 0,
                     stream, W_lin, b_lin, outp);
}

// Round 12
// 392.871 us; speedup vs baseline: 1.0437x; 1.0437x over previous
//
#include <hip/hip_runtime.h>

#define N_NODES 100000
#define N_EDGES 1600000
#define D 128
#define DE 32
#define SCAN_CHUNK 1024
#define N_CHUNKS ((N_NODES + SCAN_CHUNK - 1) / SCAN_CHUNK)  // 98
#define POS_BLOCKS (N_EDGES / 2 / 256)                      // 3125
#define XH_BLOCKS (N_NODES * D / 8 / 256)                   // 6250

// NOTE on eps: reference divides by sqrt(deg_in*deg_out)+1e-10 with both
// degrees >= 1, so the +1e-10 is a 1e-10 relative perturbation — far below
// f32 rounding. We factor w = ew * rsqrt(di) * rsqrt(do); rdo is uniform per
// dst-node, so rows accumulate with w' = ew*rdi[src] and scale by rdo once.
//
// NOTE on bf16 gather (R9): neighbor-sum reads bf16(x) (RNE) with f32
// accumulation; measured absmax 0.0039 (unchanged vs f32) vs 0.019 threshold.
//
// R11 lesson: do NOT route the 25.6MB rec stream through the scalar pipe
// (K$ misses serialize). Vector loads + readlane/bpermute broadcasts win.
// R12: u32 (2xbf16) x-loads halve hot-path vector-mem instrs; post-loop
// 4-bpermute lane transpose restores the conflict-free l/l+64 epilogue.

__device__ inline float bflo(unsigned u) {
  return __uint_as_float(u << 16);
}
__device__ inline float bfhi(unsigned u) {
  return __uint_as_float(u & 0xFFFF0000u);
}
__device__ inline unsigned pk_bf2(float lo, float hi) {
  unsigned a = __float_as_uint(lo), b = __float_as_uint(hi);
  a = (a + 0x7FFFu + ((a >> 16) & 1)) >> 16;  // RNE
  b = (b + 0x7FFFu + ((b >> 16) & 1)) >> 16;
  return a | (b << 16);
}

// ---------------------------------------------------------------------------
// K1: zero deg replicas + cursor (contiguous 5N region).
__global__ __launch_bounds__(256) void init_kernel(int* __restrict__ z) {
  int idx = blockIdx.x * 256 + threadIdx.x;
  if (idx < 5 * N_NODES) z[idx] = 0;
}

// ---------------------------------------------------------------------------
// K2 (fused): blocks [0,POS_BLOCKS) do per-edge cursor atomics (2 edges/thr);
// remaining blocks convert x -> bf16 table xh. The BW-bound xh work overlaps
// the atomic-latency-bound pos work in one dispatch.
__global__ __launch_bounds__(256) void pos_xh_kernel(
    const int4* __restrict__ el2, int* __restrict__ cursor,
    int2* __restrict__ pos2, const float4* __restrict__ x4,
    uint4* __restrict__ xh4) {
  int b = blockIdx.x;
  if (b < POS_BLOCKS) {
    int i = b * 256 + threadIdx.x;  // edge-pair index
    if (i >= N_EDGES / 2) return;
    int4 e = el2[i];
    int2 p;
    p.x = atomicAdd(&cursor[e.y], 1);
    p.y = atomicAdd(&cursor[e.w], 1);
    pos2[i] = p;
  } else {
    int i = (b - POS_BLOCKS) * 256 + threadIdx.x;
    if (i >= N_NODES * D / 8) return;
    float4 f0 = x4[2 * i], f1 = x4[2 * i + 1];
    uint4 o;
    o.x = pk_bf2(f0.x, f0.y);
    o.y = pk_bf2(f0.z, f0.w);
    o.z = pk_bf2(f1.x, f1.y);
    o.w = pk_bf2(f1.z, f1.w);
    xh4[i] = o;
  }
}

// ---------------------------------------------------------------------------
// K3a: per-1024-chunk exclusive scan of counts(=cursor) -> partial, totals.
__global__ __launch_bounds__(256) void scan1_kernel(
    const int* __restrict__ counts, int* __restrict__ partial,
    int* __restrict__ blocksum) {
  __shared__ int lds[256];
  int t = threadIdx.x;
  int base = blockIdx.x * SCAN_CHUNK + t * 4;
  int c[4];
  int s = 0;
#pragma unroll
  for (int k = 0; k < 4; k++) {
    c[k] = (base + k < N_NODES) ? counts[base + k] : 0;
    s += c[k];
  }
  lds[t] = s;
  __syncthreads();
  for (int off = 1; off < 256; off <<= 1) {
    int tmp = (t >= off) ? lds[t - off] : 0;
    __syncthreads();
    lds[t] += tmp;
    __syncthreads();
  }
  int run = lds[t] - s;
#pragma unroll
  for (int k = 0; k < 4; k++) {
    int v = base + k;
    if (v < N_NODES) partial[v] = run;
    run += c[k];
  }
  if (t == 255) blocksum[blockIdx.x] = lds[255];
}

// ---------------------------------------------------------------------------
// K3b: exclusive scan of the 98 chunk totals.
__global__ __launch_bounds__(128) void scan2_kernel(
    const int* __restrict__ blocksum, int* __restrict__ blockoff) {
  __shared__ int lds[128];
  int t = threadIdx.x;
  int v = (t < N_CHUNKS) ? blocksum[t] : 0;
  lds[t] = v;
  __syncthreads();
  for (int off = 1; off < 128; off <<= 1) {
    int tmp = (t >= off) ? lds[t - off] : 0;
    __syncthreads();
    lds[t] += tmp;
    __syncthreads();
  }
  if (t < N_CHUNKS) blockoff[t] = lds[t] - v;
}

// ---------------------------------------------------------------------------
// K4: place 16B AoS records {src, eid, ew, 0} at start[dst]+pos + deg_in
// replica atomics.
__global__ __launch_bounds__(256) void place_kernel(
    const int4* __restrict__ el2, const float2* __restrict__ ew2,
    const int2* __restrict__ pos2, const int* __restrict__ partial,
    const int* __restrict__ blockoff, float* __restrict__ deg4,
    int4* __restrict__ rec) {
  int i = blockIdx.x * 256 + threadIdx.x;  // edge-pair index
  if (i >= N_EDGES / 2) return;
  int4 e = el2[i];
  float2 w = ew2[i];
  int2 p = pos2[i];
  int r0 = (threadIdx.x & 3) * N_NODES;
  atomicAdd(&deg4[r0 + e.x], w.x);
  atomicAdd(&deg4[r0 + e.z], w.y);
  int4 rA, rB;
  rA.x = e.x; rA.y = 2 * i;     rA.z = __float_as_int(w.x); rA.w = 0;
  rB.x = e.z; rB.y = 2 * i + 1; rB.z = __float_as_int(w.y); rB.w = 0;
  rec[partial[e.y] + blockoff[e.y >> 10] + p.x] = rA;
  rec[partial[e.w] + blockoff[e.w >> 10] + p.y] = rB;
}

// ---------------------------------------------------------------------------
// K5: finalize rdi = rsqrt(1 + sum of 4 deg replicas).
__global__ __launch_bounds__(256) void rdi_kernel(
    const float* __restrict__ deg4, float* __restrict__ rdi) {
  int v = blockIdx.x * 256 + threadIdx.x;
  if (v >= N_NODES) return;
  rdi[v] = rsqrtf(1.f + deg4[v] + deg4[N_NODES + v] + deg4[2 * N_NODES + v] +
                  deg4[3 * N_NODES + v]);
}

// ---------------------------------------------------------------------------
// K6: single-pass fused gather (ef + x + row epilogue). One wave per node.
// R10 structure (vector rec loads + shfl broadcasts). Lane l accumulates
// dims 2l,2l+1 via one u32 (2xbf16) load per x-row; after the loop a
// 4-bpermute lane transpose converts to the l/l+64 layout so the proven
// conflict-free we[.*36] epilogue applies. 8 edges/iter for MLP.
template <bool BF16>
__global__ __launch_bounds__(256) void gather_fused_kernel(
    const float* __restrict__ x, const ushort* __restrict__ xh,
    const float* __restrict__ ef, const int* __restrict__ partial,
    const int* __restrict__ blockoff, const int* __restrict__ counts,
    const int4* __restrict__ rec, const float* __restrict__ rdi,
    const float* __restrict__ W_edge, const float* __restrict__ b_edge,
    float* __restrict__ out) {
  __shared__ __align__(16) float we[128 * 36];
  __shared__ float beS[128];
  int t = threadIdx.x;
#pragma unroll
  for (int i = 0; i < 4; ++i) {  // 1024 float4 / 256 threads
    int f = t + i * 256;
    int r = f >> 3, kq = f & 7;
    *(float4*)&we[r * 36 + 4 * kq] = *(const float4*)&W_edge[r * DE + 4 * kq];
  }
  if (t < 128) beS[t] = b_edge[t];
  __syncthreads();

  int wid = t >> 6, lane = t & 63;
  int v = blockIdx.x * 4 + wid;
  if (v >= N_NODES) return;
  int start = partial[v] + blockoff[v >> 10];
  int cnt = counts[v];
  int lane31 = lane & 31;
  bool lowhalf = lane < 32;

  float A0 = 0.f, A1 = 0.f, B0 = 0.f, B1 = 0.f;
  float C0 = 0.f, C1 = 0.f, E0 = 0.f, E1 = 0.f;
  float ga = 0.f, gb = 0.f, gc = 0.f, gd = 0.f, dsum = 0.f, wsv = 0.f;

  for (int base = 0; base < cnt; base += 64) {
    int nb = cnt - base;
    if (nb > 64) nb = 64;
    int s_l = 0, e_l = 0;
    float w_l = 0.f;
    if (lane < nb) {
      int4 r = rec[start + base + lane];
      s_l = r.x;
      e_l = r.y;
      float wraw = __int_as_float(r.z);
      w_l = wraw * rdi[r.x];
      dsum += wraw;
      wsv += w_l;
    }
    int i = 0;
    for (; i + 8 <= nb; i += 8) {
      int s0 = __shfl(s_l, i + 0), s1 = __shfl(s_l, i + 1);
      int s2 = __shfl(s_l, i + 2), s3 = __shfl(s_l, i + 3);
      int s4 = __shfl(s_l, i + 4), s5 = __shfl(s_l, i + 5);
      int s6 = __shfl(s_l, i + 6), s7 = __shfl(s_l, i + 7);
      float w0 = __shfl(w_l, i + 0), w1 = __shfl(w_l, i + 1);
      float w2 = __shfl(w_l, i + 2), w3 = __shfl(w_l, i + 3);
      float w4 = __shfl(w_l, i + 4), w5 = __shfl(w_l, i + 5);
      float w6 = __shfl(w_l, i + 6), w7 = __shfl(w_l, i + 7);
      // ef: 4 half-wave loads; weights reuse w0..w7 via select
      int hh = lane >> 5;
      int eA = __shfl(e_l, i + 0 + hh), eB = __shfl(e_l, i + 2 + hh);
      int eC = __shfl(e_l, i + 4 + hh), eD = __shfl(e_l, i + 6 + hh);
      float wA = lowhalf ? w0 : w1, wB = lowhalf ? w2 : w3;
      float wC = lowhalf ? w4 : w5, wD = lowhalf ? w6 : w7;
      ga = fmaf(wA, __builtin_nontemporal_load(&ef[(size_t)eA * DE + lane31]),
                ga);
      gb = fmaf(wB, __builtin_nontemporal_load(&ef[(size_t)eB * DE + lane31]),
                gb);
      gc = fmaf(wC, __builtin_nontemporal_load(&ef[(size_t)eC * DE + lane31]),
                gc);
      gd = fmaf(wD, __builtin_nontemporal_load(&ef[(size_t)eD * DE + lane31]),
                gd);
      if (BF16) {
        unsigned u0 = ((const unsigned*)(xh + (size_t)s0 * D))[lane];
        unsigned u1 = ((const unsigned*)(xh + (size_t)s1 * D))[lane];
        unsigned u2 = ((const unsigned*)(xh + (size_t)s2 * D))[lane];
        unsigned u3 = ((const unsigned*)(xh + (size_t)s3 * D))[lane];
        unsigned u4 = ((const unsigned*)(xh + (size_t)s4 * D))[lane];
        unsigned u5 = ((const unsigned*)(xh + (size_t)s5 * D))[lane];
        unsigned u6 = ((const unsigned*)(xh + (size_t)s6 * D))[lane];
        unsigned u7 = ((const unsigned*)(xh + (size_t)s7 * D))[lane];
        A0 = fmaf(w0, bflo(u0), A0); A1 = fmaf(w0, bfhi(u0), A1);
        B0 = fmaf(w1, bflo(u1), B0); B1 = fmaf(w1, bfhi(u1), B1);
        C0 = fmaf(w2, bflo(u2), C0); C1 = fmaf(w2, bfhi(u2), C1);
        E0 = fmaf(w3, bflo(u3), E0); E1 = fmaf(w3, bfhi(u3), E1);
        A0 = fmaf(w4, bflo(u4), A0); A1 = fmaf(w4, bfhi(u4), A1);
        B0 = fmaf(w5, bflo(u5), B0); B1 = fmaf(w5, bfhi(u5), B1);
        C0 = fmaf(w6, bflo(u6), C0); C1 = fmaf(w6, bfhi(u6), C1);
        E0 = fmaf(w7, bflo(u7), E0); E1 = fmaf(w7, bfhi(u7), E1);
      } else {
        float2 u0 = ((const float2*)(x + (size_t)s0 * D))[lane];
        float2 u1 = ((const float2*)(x + (size_t)s1 * D))[lane];
        float2 u2 = ((const float2*)(x + (size_t)s2 * D))[lane];
        float2 u3 = ((const float2*)(x + (size_t)s3 * D))[lane];
        float2 u4 = ((const float2*)(x + (size_t)s4 * D))[lane];
        float2 u5 = ((const float2*)(x + (size_t)s5 * D))[lane];
        float2 u6 = ((const float2*)(x + (size_t)s6 * D))[lane];
        float2 u7 = ((const float2*)(x + (size_t)s7 * D))[lane];
        A0 = fmaf(w0, u0.x, A0); A1 = fmaf(w0, u0.y, A1);
        B0 = fmaf(w1, u1.x, B0); B1 = fmaf(w1, u1.y, B1);
        C0 = fmaf(w2, u2.x, C0); C1 = fmaf(w2, u2.y, C1);
        E0 = fmaf(w3, u3.x, E0); E1 = fmaf(w3, u3.y, E1);
        A0 = fmaf(w4, u4.x, A0); A1 = fmaf(w4, u4.y, A1);
        B0 = fmaf(w5, u5.x, B0); B1 = fmaf(w5, u5.y, B1);
        C0 = fmaf(w6, u6.x, C0); C1 = fmaf(w6, u6.y, C1);
        E0 = fmaf(w7, u7.x, E0); E1 = fmaf(w7, u7.y, E1);
      }
    }
    for (; i + 2 <= nb; i += 2) {
      int s0 = __shfl(s_l, i), s1 = __shfl(s_l, i + 1);
      float w0 = __shfl(w_l, i), w1 = __shfl(w_l, i + 1);
      int eE = __shfl(e_l, i + (lane >> 5));
      float wE = lowhalf ? w0 : w1;
      ga = fmaf(wE, __builtin_nontemporal_load(&ef[(size_t)eE * DE + lane31]),
                ga);
      if (BF16) {
        unsigned u0 = ((const unsigned*)(xh + (size_t)s0 * D))[lane];
        unsigned u1 = ((const unsigned*)(xh + (size_t)s1 * D))[lane];
        A0 = fmaf(w0, bflo(u0), A0); A1 = fmaf(w0, bfhi(u0), A1);
        B0 = fmaf(w1, bflo(u1), B0); B1 = fmaf(w1, bfhi(u1), B1);
      } else {
        float2 u0 = ((const float2*)(x + (size_t)s0 * D))[lane];
        float2 u1 = ((const float2*)(x + (size_t)s1 * D))[lane];
        A0 = fmaf(w0, u0.x, A0); A1 = fmaf(w0, u0.y, A1);
        B0 = fmaf(w1, u1.x, B0); B1 = fmaf(w1, u1.y, B1);
      }
    }
    if (i < nb) {
      int s0 = __shfl(s_l, i);
      float w0 = __shfl(w_l, i);
      int eA = __shfl(e_l, i);
      if (lowhalf)
        ga = fmaf(w0,
                  __builtin_nontemporal_load(&ef[(size_t)eA * DE + lane31]),
                  ga);
      if (BF16) {
        unsigned u0 = ((const unsigned*)(xh + (size_t)s0 * D))[lane];
        A0 = fmaf(w0, bflo(u0), A0);
        A1 = fmaf(w0, bfhi(u0), A1);
      } else {
        float2 u0 = ((const float2*)(x + (size_t)s0 * D))[lane];
        A0 = fmaf(w0, u0.x, A0);
        A1 = fmaf(w0, u0.y, A1);
      }
    }
  }
  float a0 = (A0 + B0) + (C0 + E0);  // dim 2*lane
  float a1 = (A1 + B1) + (C1 + E1);  // dim 2*lane+1
#pragma unroll
  for (int off = 32; off; off >>= 1) {
    dsum += __shfl_xor(dsum, off);
    wsv += __shfl_xor(wsv, off);
  }
  float rdo = rsqrtf(1.f + dsum);
  float gfull = (ga + gb) + (gc + gd);
  gfull += __shfl(gfull, (lane + 32) & 63);  // lanes 0..31 hold full g_k
  float gk = gfull;

  // lane transpose: (2l,2l+1) layout -> (l, l+64)
  int half = lane >> 1;
  float v0 = __shfl(a0, half), v1 = __shfl(a1, half);
  float accLo = (lane & 1) ? v1 : v0;  // dim = lane
  float q0 = __shfl(a0, 32 + half), q1 = __shfl(a1, 32 + half);
  float accHi = (lane & 1) ? q1 : q0;  // dim = lane + 64

  // epilogue (pre-rdo accumulation; one scale at the end)
  size_t ro = (size_t)v * D;
  float xs0, xs1;
  if (BF16) {
    xs0 = bflo((unsigned)xh[ro + lane] << 16) , xs1 = 0.f;
    xs0 = __uint_as_float((unsigned)xh[ro + lane] << 16);
    xs1 = __uint_as_float((unsigned)xh[ro + lane + 64] << 16);
  } else {
    xs0 = x[ro + lane];
    xs1 = x[ro + lane + 64];
  }
  float rdiv = rdi[v];
  float s0 = accLo + rdiv * xs0 + wsv * beS[lane];
  float s1 = accHi + rdiv * xs1 + wsv * beS[lane + 64];
#pragma unroll
  for (int kq = 0; kq < 8; ++kq) {
    float4 w0 = *(const float4*)&we[lane * 36 + 4 * kq];
    float4 w1 = *(const float4*)&we[(lane + 64) * 36 + 4 * kq];
    float g0 = __shfl(gk, 4 * kq);
    float g1 = __shfl(gk, 4 * kq + 1);
    float g2 = __shfl(gk, 4 * kq + 2);
    float g3 = __shfl(gk, 4 * kq + 3);
    s0 += g0 * w0.x + g1 * w0.y + g2 * w0.z + g3 * w0.w;
    s1 += g0 * w1.x + g1 * w1.y + g2 * w1.z + g3 * w1.w;
  }
  out[ro + lane] = rdo * s0;
  out[ro + lane + 64] = rdo * s1;
}

// ---------------------------------------------------------------------------
// K7: in-place per-128-row-tile SGEMM: out = relu(out @ W_lin^T + b_lin).
// __launch_bounds__(256,3) + rolled kq-loop + one-b-at-a-time keeps VGPR low
// (R7 failure: 256 VGPR, 8.8% occupancy).
__global__ __launch_bounds__(256, 3) void gemm2_kernel(
    const float* __restrict__ W_lin, const float* __restrict__ b_lin,
    float* __restrict__ out) {
  __shared__ __align__(16) float xs[128 * 32];
  __shared__ __align__(16) float wl[128 * 32];
  int t = threadIdx.x;
  int tn = t & 15, tm = t >> 4;
  int m0 = 4 * tm, n0 = 4 * tn;
  int vbase = blockIdx.x * 128;
  float acc[8][8] = {};

  for (int ks = 0; ks < D; ks += 32) {
    __syncthreads();
#pragma unroll
    for (int i = 0; i < 4; ++i) {
      int f = t + i * 256;
      int r = f >> 3, kq = f & 7;
      int sw = (4 * kq) ^ (4 * ((r >> 2) & 7));
      float4 xv = make_float4(0.f, 0.f, 0.f, 0.f);
      if (vbase + r < N_NODES)
        xv = *(const float4*)&out[(size_t)(vbase + r) * D + ks + 4 * kq];
      *(float4*)&xs[r * 32 + sw] = xv;
      *(float4*)&wl[r * 32 + sw] = *(const float4*)&W_lin[r * D + ks + 4 * kq];
    }
    __syncthreads();
#pragma unroll 1
    for (int kq = 0; kq < 8; ++kq) {
      int sa = (4 * kq) ^ (4 * (tm & 7));
      int sb = (4 * kq) ^ (4 * (tn & 7));
      float4 a[8];
#pragma unroll
      for (int i = 0; i < 4; ++i) {
        a[i] = *(const float4*)&xs[(m0 + i) * 32 + sa];
        a[4 + i] = *(const float4*)&xs[(m0 + 64 + i) * 32 + sa];
      }
#pragma unroll
      for (int j = 0; j < 8; ++j) {
        int rj = (j < 4) ? (n0 + j) : (n0 + 60 + j);
        float4 b = *(const float4*)&wl[rj * 32 + sb];
#pragma unroll
        for (int i = 0; i < 8; ++i) {
          acc[i][j] += a[i].x * b.x + a[i].y * b.y + a[i].z * b.z +
                       a[i].w * b.w;
        }
      }
    }
  }

  float bl[8];
#pragma unroll
  for (int j = 0; j < 4; ++j) {
    bl[j] = b_lin[n0 + j];
    bl[4 + j] = b_lin[n0 + 64 + j];
  }
#pragma unroll
  for (int i = 0; i < 8; ++i) {
    int m = vbase + m0 + (i < 4 ? i : 64 + i - 4);
    if (m >= N_NODES) continue;
    float4 o0, o1;
    o0.x = fmaxf(acc[i][0] + bl[0], 0.f);
    o0.y = fmaxf(acc[i][1] + bl[1], 0.f);
    o0.z = fmaxf(acc[i][2] + bl[2], 0.f);
    o0.w = fmaxf(acc[i][3] + bl[3], 0.f);
    o1.x = fmaxf(acc[i][4] + bl[4], 0.f);
    o1.y = fmaxf(acc[i][5] + bl[5], 0.f);
    o1.z = fmaxf(acc[i][6] + bl[6], 0.f);
    o1.w = fmaxf(acc[i][7] + bl[7], 0.f);
    *(float4*)&out[(size_t)m * D + n0] = o0;
    *(float4*)&out[(size_t)m * D + n0 + 64] = o1;
  }
}

// ---------------------------------------------------------------------------
extern "C" void kernel_launch(void* const* d_in, const int* in_sizes, int n_in,
                              void* d_out, int out_size, void* d_ws,
                              size_t ws_size, hipStream_t stream) {
  const float* x      = (const float*)d_in[0];
  const int*   el     = (const int*)d_in[1];
  const float* ew     = (const float*)d_in[2];
  const float* ef     = (const float*)d_in[3];
  const float* W_lin  = (const float*)d_in[4];
  const float* b_lin  = (const float*)d_in[5];
  const float* W_edge = (const float*)d_in[6];
  const float* b_edge = (const float*)d_in[7];

  float* outp = (float*)d_out;  // fused gather writes rows; gemm2 in place

  // workspace layout (~60.4 MB with xh; fallback ~34.8 MB without)
  char* base = (char*)d_ws;
  size_t off = 0;
  int4* rec      = (int4*)(base + off); off += (size_t)N_EDGES * 16;
  ushort* xh     = (ushort*)(base + off); off += (size_t)N_NODES * D * 2;
  int*  pos      = (int*)(base + off);  off += (size_t)N_EDGES * 4;
  float* deg4    = (float*)(base + off); off += (size_t)4 * N_NODES * 4;
  int*  cursor   = (int*)(base + off);  off += (size_t)N_NODES * 4;
  int*  partial  = (int*)(base + off);  off += (size_t)N_NODES * 4;
  int*  blocksum = (int*)(base + off);  off += 512;
  int*  blockoff = (int*)(base + off);  off += 512;
  float* rdi     = (float*)(base + off); off += (size_t)N_NODES * 4;
  const size_t REQ_FAST = off;
  bool fast = (ws_size >= REQ_FAST);
  if (!fast) {
    // fallback layout: drop xh, shift everything after it down 25.6MB
    off = (size_t)N_EDGES * 16;
    pos      = (int*)(base + off);  off += (size_t)N_EDGES * 4;
    deg4     = (float*)(base + off); off += (size_t)4 * N_NODES * 4;
    cursor   = (int*)(base + off);  off += (size_t)N_NODES * 4;
    partial  = (int*)(base + off);  off += (size_t)N_NODES * 4;
    blocksum = (int*)(base + off);  off += 512;
    blockoff = (int*)(base + off);  off += 512;
    rdi      = (float*)(base + off); off += (size_t)N_NODES * 4;
    xh       = nullptr;
  }

  hipLaunchKernelGGL(init_kernel, dim3((5 * N_NODES + 255) / 256), dim3(256),
                     0, stream, (int*)deg4);
  // fused pos + (fast ? xh-build : nothing)
  hipLaunchKernelGGL(pos_xh_kernel,
                     dim3(fast ? POS_BLOCKS + XH_BLOCKS : POS_BLOCKS),
                     dim3(256), 0, stream, (const int4*)el, cursor, (int2*)pos,
                     (const float4*)x, (uint4*)xh);
  hipLaunchKernelGGL(scan1_kernel, dim3(N_CHUNKS), dim3(256), 0, stream,
                     cursor, partial, blocksum);
  hipLaunchKernelGGL(scan2_kernel, dim3(1), dim3(128), 0, stream, blocksum,
                     blockoff);
  hipLaunchKernelGGL(place_kernel, dim3((N_EDGES / 2 + 255) / 256), dim3(256),
                     0, stream, (const int4*)el, (const float2*)ew,
                     (const int2*)pos, partial, blockoff, deg4, rec);
  hipLaunchKernelGGL(rdi_kernel, dim3((N_NODES + 255) / 256), dim3(256), 0,
                     stream, deg4, rdi);
  if (fast) {
    hipLaunchKernelGGL(gather_fused_kernel<true>, dim3((N_NODES + 3) / 4),
                       dim3(256), 0, stream, x, xh, ef, partial, blockoff,
                       cursor, rec, rdi, W_edge, b_edge, outp);
  } else {
    hipLaunchKernelGGL(gather_fused_kernel<false>, dim3((N_NODES + 3) / 4),
                       dim3(256), 0, stream, x, xh, ef, partial, blockoff,
                       cursor, rec, rdi, W_edge, b_edge, outp);
  }
  hipLaunchKernelGGL(gemm2_kernel, dim3((N_NODES + 127) / 128), dim3(256), 0,
                     stream, W_lin, b_lin, outp);
}